// Round 9
// baseline (113.859 us; speedup 1.0000x reference)
//
#include <hip/hip_runtime.h>
#include <stdint.h>

// ExpertLoRA: N=8192, Z=1024, H=2048, W=64, R=8, SCALE=1.0
// Round 8: no-LDS / no-barrier max-TLP design. One token per wave,
// 8 waves/block (block = L1 locality group for one expert), 1088 blocks
// -> 8.5 waves/SIMD. All weight reads coalescing-correct from global:
//   a1/a2: float4/scalar, lane-contiguous rows (L1 broadcast across waves)
//   b1/b2: one h (or d) row per lane -> 32 B/lane @ 32-B stride
// Reductions are wave-local (__shfl_xor), zero __syncthreads.

constexpr int Zd = 1024;
constexpr int Hd = 2048;
constexpr int Rr = 8;
constexpr int Wn = 64;
constexpr int TB = 8;            // tokens per block = waves per block
constexpr int NT = 512;          // threads per block (8 waves)
constexpr float kScale = 1.0f;

// ws layout (ints): [0]=n_blocks, [16..16+N)=order, then int4 block table.

__global__ __launch_bounds__(1024) void bucket_kernel(
    const int* __restrict__ a_idx, int N, int* __restrict__ ws)
{
    __shared__ int hist[Wn];
    __shared__ int cursor[Wn];
    const int t = threadIdx.x;
    if (t < Wn) hist[t] = 0;
    __syncthreads();
    for (int i = t; i < N / 4; i += 1024) {
        const int4 v = ((const int4*)a_idx)[i];
        atomicAdd(&hist[v.x], 1); atomicAdd(&hist[v.y], 1);
        atomicAdd(&hist[v.z], 1); atomicAdd(&hist[v.w], 1);
    }
    for (int i = (N & ~3) + t; i < N; i += 1024) atomicAdd(&hist[a_idx[i]], 1);
    __syncthreads();

    if (t < Wn) {                       // wave 0 does both prefix scans
        const int c = hist[t];
        int scan = c;
#pragma unroll
        for (int off = 1; off < 64; off <<= 1) {
            const int v = __shfl_up(scan, off, 64);
            if (t >= off) scan += v;
        }
        const int base = scan - c;

        const int nb_e = (c + TB - 1) / TB;
        int bs = nb_e;
#pragma unroll
        for (int off = 1; off < 64; off <<= 1) {
            const int v = __shfl_up(bs, off, 64);
            if (t >= off) bs += v;
        }
        const int bstart = bs - nb_e;
        if (t == Wn - 1) ws[0] = bs;
        cursor[t] = base;

        int4* btab = (int4*)(ws + 16 + N);
        for (int s = 0, k = 0; s < c; s += TB, ++k)
            btab[bstart + k] = make_int4(t, base + s, min(TB, c - s), 0);
    }
    __syncthreads();
    int* order = ws + 16;
    for (int i = t; i < N / 4; i += 1024) {
        const int4 v = ((const int4*)a_idx)[i];
        order[atomicAdd(&cursor[v.x], 1)] = 4 * i + 0;
        order[atomicAdd(&cursor[v.y], 1)] = 4 * i + 1;
        order[atomicAdd(&cursor[v.z], 1)] = 4 * i + 2;
        order[atomicAdd(&cursor[v.w], 1)] = 4 * i + 3;
    }
    for (int i = (N & ~3) + t; i < N; i += 1024)
        order[atomicAdd(&cursor[a_idx[i]], 1)] = i;
}

__device__ __forceinline__ float wave_allreduce(float v) {
#pragma unroll
    for (int off = 1; off < 64; off <<= 1)
        v += __shfl_xor(v, off, 64);
    return v;
}

__device__ __forceinline__ float dot8(const float* t, float4 w0, float4 w1) {
    return fmaf(t[0], w0.x, fmaf(t[1], w0.y, fmaf(t[2], w0.z, fmaf(t[3], w0.w,
           fmaf(t[4], w1.x, fmaf(t[5], w1.y, fmaf(t[6], w1.z, t[7] * w1.w)))))));
}

__device__ __forceinline__ float silu(float x) {
    return x * __builtin_amdgcn_rcpf(1.f + __expf(-x));
}

__global__ __launch_bounds__(NT, 8) void lora_main(
    const float* __restrict__ z,        // [N, Z]
    const float* __restrict__ h_pre,    // [N, H]
    const float* __restrict__ out_pre,  // [N, Z]
    const float* __restrict__ a1,       // [W, R, Z]
    const float* __restrict__ b1,       // [W, H, R]
    const float* __restrict__ a2,       // [W, R, H]
    const float* __restrict__ b2,       // [W, Z, R]
    float* __restrict__ out,            // [N, Z]
    const int* __restrict__ ws, int N)
{
    // XCD-aware swizzle: contiguous logical blocks (= same/adjacent expert)
    // land on one XCD's L2 (expert slice ~1.5 MB/XCD).
    const int cpx = gridDim.x >> 3;
    const int lb  = (blockIdx.x & 7) * cpx + (blockIdx.x >> 3);
    if (lb >= ws[0]) return;

    const int4 desc = ((const int4*)(ws + 16 + N))[lb];
    const int e = desc.x, start = desc.y, cnt = desc.z;
    const int* order = ws + 16;

    const int wave = threadIdx.x >> 6;
    const int lane = threadIdx.x & 63;

    const bool val = (wave < cnt);
    const int  tok = order[start + (val ? wave : 0)];

    const float4* A1  = (const float4*)(a1 + (size_t)e * (Rr * Zd));
    const float*  b1e = b1 + (size_t)e * (Hd * Rr);
    const float*  a2e = a2 + (size_t)e * (Rr * Hd);
    const float*  b2e = b2 + (size_t)e * (Zd * Rr);

    // ---------- Phase 1: t1[r] = sum_d z[tok,d] * a1[e,r,d] ----------
    // lane owns float4 d-slice; a1 rows lane-contiguous (L1 broadcast).
    const float4* Zp = (const float4*)(z + (size_t)tok * Zd);

    float p[Rr];
#pragma unroll
    for (int r = 0; r < Rr; ++r) p[r] = 0.f;

#pragma unroll
    for (int i = 0; i < Zd / 4 / 64; ++i) {         // 4 iters
        const int c = lane + i * 64;
        const float4 zv = Zp[c];
#pragma unroll
        for (int r = 0; r < Rr; ++r) {
            const float4 w = A1[r * (Zd / 4) + c];
            p[r] = fmaf(zv.x, w.x, fmaf(zv.y, w.y,
                   fmaf(zv.z, w.z, fmaf(zv.w, w.w, p[r]))));
        }
    }
    float t1[Rr];
#pragma unroll
    for (int r = 0; r < Rr; ++r) t1[r] = wave_allreduce(p[r]);

    // ---------- Phase 2: one h per lane; q[r] = sum_h silu(...)·a2[r,h] ----
    // b1 row h = 32 B contiguous per lane (stride 32 B across lanes);
    // h_pre and a2[r,*] are perfectly lane-coalesced scalars.
    const float* hrow = h_pre + (size_t)tok * Hd;

    float q[Rr];
#pragma unroll
    for (int r = 0; r < Rr; ++r) q[r] = 0.f;

#pragma unroll 2
    for (int i = 0; i < Hd / 64; ++i) {             // 32 iters
        const int h = i * 64 + lane;
        const float  hv = hrow[h];
        const float4 w0 = *(const float4*)(b1e + (size_t)h * Rr);
        const float4 w1 = *(const float4*)(b1e + (size_t)h * Rr + 4);
        const float x  = hv + dot8(t1, w0, w1) * kScale;
        const float sv = silu(x);
#pragma unroll
        for (int r = 0; r < Rr; ++r)
            q[r] = fmaf(sv, a2e[r * Hd + h], q[r]);
    }
    float t2[Rr];
#pragma unroll
    for (int r = 0; r < Rr; ++r) t2[r] = wave_allreduce(q[r]) * kScale;

    // ---------- Phase 3: one d per lane; out = out_pre + t2·b2[e,d,:] ------
    const float* orow = out_pre + (size_t)tok * Zd;
    float*       xrow = out + (size_t)tok * Zd;

#pragma unroll 2
    for (int i = 0; i < Zd / 64; ++i) {             // 16 iters
        const int d = i * 64 + lane;
        const float4 w0 = *(const float4*)(b2e + (size_t)d * Rr);
        const float4 w1 = *(const float4*)(b2e + (size_t)d * Rr + 4);
        const float res = orow[d] + dot8(t2, w0, w1);
        if (val) xrow[d] = res;
    }
}

extern "C" void kernel_launch(void* const* d_in, const int* in_sizes, int n_in,
                              void* d_out, int out_size, void* d_ws, size_t ws_size,
                              hipStream_t stream) {
    const float* z       = (const float*)d_in[0];
    const int*   a_idx   = (const int*)d_in[1];
    const float* h_pre   = (const float*)d_in[2];
    const float* out_pre = (const float*)d_in[3];
    const float* a1      = (const float*)d_in[4];
    const float* b1      = (const float*)d_in[5];
    const float* a2      = (const float*)d_in[6];
    const float* b2      = (const float*)d_in[7];
    float* out = (float*)d_out;

    const int N = in_sizes[1];  // a_idx count

    bucket_kernel<<<1, 1024, 0, stream>>>(a_idx, N, (int*)d_ws);

    int nwg = N / TB + Wn;              // 1088 blocks (incl. per-expert tails)
    nwg = (nwg + 7) & ~7;               // multiple of 8 for XCD swizzle
    lora_main<<<nwg, NT, 0, stream>>>(z, h_pre, out_pre, a1, b1, a2, b2, out,
                                      (const int*)d_ws, N);
}

// Round 10
// 70.351 us; speedup vs baseline: 1.6184x; 1.6184x over previous
//
#include <hip/hip_runtime.h>
#include <stdint.h>

// ExpertLoRA: N=8192, Z=1024, H=2048, W=64, R=8, SCALE=1.0
// Round 9: R6-design counted-vmcnt pipeline with LDS cut 80->48 KB:
//  - a1 read direct from global (float4 row-coalesced, L1-shared by 8 waves)
//  - phase-2 b1/a2 3-deep chunk pool (6 x 8 KB slots)
//  - b2 staged into the pool slots freed by the chunk rotation at kc=6,7
// 48 KB -> 3 blocks/CU -> all 576 blocks co-resident (no tail dispatch).

constexpr int Zd = 1024;
constexpr int Hd = 2048;
constexpr int Rr = 8;
constexpr int Wn = 64;
constexpr int TB = 16;           // tokens per block
constexpr int TW = 2;            // tokens per wave
constexpr int NT = 512;          // threads per block (8 waves)
constexpr int HC = 256;          // phase-2 H chunk (elements)
constexpr int NCHUNK = Hd / HC;  // 8
constexpr float kScale = 1.0f;

// chunk buffer b (b=0,1,2) -> b1 slot byte base SB[b], a2 slot = SB[b]+8192.
// Slot order {2,3},{4,5},{0,1} so b2 segs 0..3 land flat at bytes [0,32768).
__device__ __constant__ int kSB[3] = {16384, 32768, 0};

// ws layout (ints): [0]=n_blocks, [16..16+N)=order, then int4 block table.

__global__ __launch_bounds__(1024) void bucket_kernel(
    const int* __restrict__ a_idx, int N, int* __restrict__ ws)
{
    __shared__ int hist[Wn];
    __shared__ int cursor[Wn];
    const int t = threadIdx.x;
    if (t < Wn) hist[t] = 0;
    __syncthreads();
    for (int i = t; i < N / 4; i += 1024) {
        const int4 v = ((const int4*)a_idx)[i];
        atomicAdd(&hist[v.x], 1); atomicAdd(&hist[v.y], 1);
        atomicAdd(&hist[v.z], 1); atomicAdd(&hist[v.w], 1);
    }
    for (int i = (N & ~3) + t; i < N; i += 1024) atomicAdd(&hist[a_idx[i]], 1);
    __syncthreads();

    if (t < Wn) {                       // wave 0 does both prefix scans
        const int c = hist[t];
        int scan = c;
#pragma unroll
        for (int off = 1; off < 64; off <<= 1) {
            const int v = __shfl_up(scan, off, 64);
            if (t >= off) scan += v;
        }
        const int base = scan - c;

        const int nb_e = (c + TB - 1) / TB;
        int bs = nb_e;
#pragma unroll
        for (int off = 1; off < 64; off <<= 1) {
            const int v = __shfl_up(bs, off, 64);
            if (t >= off) bs += v;
        }
        const int bstart = bs - nb_e;
        if (t == Wn - 1) ws[0] = bs;
        cursor[t] = base;

        int4* btab = (int4*)(ws + 16 + N);
        for (int s = 0, k = 0; s < c; s += TB, ++k)
            btab[bstart + k] = make_int4(t, base + s, min(TB, c - s), 0);
    }
    __syncthreads();
    int* order = ws + 16;
    for (int i = t; i < N / 4; i += 1024) {
        const int4 v = ((const int4*)a_idx)[i];
        order[atomicAdd(&cursor[v.x], 1)] = 4 * i + 0;
        order[atomicAdd(&cursor[v.y], 1)] = 4 * i + 1;
        order[atomicAdd(&cursor[v.z], 1)] = 4 * i + 2;
        order[atomicAdd(&cursor[v.w], 1)] = 4 * i + 3;
    }
    for (int i = (N & ~3) + t; i < N; i += 1024)
        order[atomicAdd(&cursor[a_idx[i]], 1)] = i;
}

__device__ __forceinline__ float wave_allreduce(float v) {
#pragma unroll
    for (int off = 1; off < 64; off <<= 1)
        v += __shfl_xor(v, off, 64);
    return v;
}

__device__ __forceinline__ float dot8(const float* t, float4 w0, float4 w1) {
    return fmaf(t[0], w0.x, fmaf(t[1], w0.y, fmaf(t[2], w0.z, fmaf(t[3], w0.w,
           fmaf(t[4], w1.x, fmaf(t[5], w1.y, fmaf(t[6], w1.z, t[7] * w1.w)))))));
}

__device__ __forceinline__ float silu(float x) {
    return x * __builtin_amdgcn_rcpf(1.f + __expf(-x));
}

// XOR swizzle: involution on byte offsets (bits 4-6 ^= bits 7-9).
__device__ __forceinline__ int swz(int o) {
    return o ^ (((o >> 7) & 7) << 4);
}

// async global -> LDS, 16 B per lane. LDS dest is wave-uniform base
// (HW adds lane*16); global src is per-lane.
__device__ __forceinline__ void stage16(const void* g, void* l) {
    __builtin_amdgcn_global_load_lds(
        (const __attribute__((address_space(1))) uint32_t*)g,
        (__attribute__((address_space(3))) uint32_t*)l, 16, 0, 0);
}

// Counted waits + raw barrier (no compiler vmcnt(0) drain).
#define WAITVM(N) asm volatile("s_waitcnt vmcnt(" #N ")" ::: "memory")
#define SYNC()    asm volatile("s_waitcnt lgkmcnt(0)\ns_barrier" ::: "memory")

__global__ __launch_bounds__(NT, 6) void lora_main(
    const float* __restrict__ z,        // [N, Z]
    const float* __restrict__ h_pre,    // [N, H]
    const float* __restrict__ out_pre,  // [N, Z]
    const float* __restrict__ a1,       // [W, R, Z]
    const float* __restrict__ b1,       // [W, H, R]
    const float* __restrict__ a2,       // [W, R, H]
    const float* __restrict__ b2,       // [W, Z, R]
    float* __restrict__ out,            // [N, Z]
    const int* __restrict__ ws, int N)
{
    __shared__ float s_pool_f[12288];   // 48 KB: 6 x 8 KB slots
    char* pool = (char*)s_pool_f;

    const int cpx = gridDim.x >> 3;
    const int lb  = (blockIdx.x & 7) * cpx + (blockIdx.x >> 3);
    if (lb >= ws[0]) return;

    const int4 desc = ((const int4*)(ws + 16 + N))[lb];
    const int e = desc.x, start = desc.y, cnt = desc.z;
    const int* order = ws + 16;

    const int t    = threadIdx.x;
    const int wave = t >> 6;
    const int lane = t & 63;

    bool val[TW];
    int  tok[TW];
#pragma unroll
    for (int k = 0; k < TW; ++k) {
        const int idx = wave * TW + k;
        val[k] = (idx < cnt);
        tok[k] = order[start + (val[k] ? idx : 0)];
    }

    const float4* A1  = (const float4*)(a1 + (size_t)e * (Rr * Zd));
    const char*   b1e = (const char*)(b1 + (size_t)e * (Hd * Rr));
    const float*  a2e = a2 + (size_t)e * (Rr * Hd);
    const char*   b2e = (const char*)(b2 + (size_t)e * (Zd * Rr));

    // ---- prologue staging: chunk 0 -> buf0, chunk 1 -> buf1; hv0 regs ----
#pragma unroll
    for (int c0 = 0; c0 < 2; ++c0) {
        stage16(b1e + (size_t)(c0 * HC) * Rr * 4 + swz(t * 16),
                pool + kSB[c0] + wave * 1024);
        stage16(a2e + wave * Hd + c0 * HC + lane * 4,
                pool + kSB[c0] + 8192 + wave * 1024);
    }
    float4 hv[2][TW];                     // hv[kc&1] = current chunk's h_pre
#pragma unroll
    for (int k = 0; k < TW; ++k)
        hv[0][k] = *(const float4*)(h_pre + (size_t)tok[k] * Hd + 4 * lane);

    // ---------- Phase 1: t1[k][r] = sum_d z[tok,d] * a1[e,r,d] (global) ----
    float p[TW][Rr];
#pragma unroll
    for (int k = 0; k < TW; ++k)
#pragma unroll
        for (int r = 0; r < Rr; ++r) p[k][r] = 0.f;

#pragma unroll
    for (int i = 0; i < Zd / 4 / 64; ++i) {         // 4 iters
        const int c = lane + i * 64;
        float4 zv[TW];
#pragma unroll
        for (int k = 0; k < TW; ++k)
            zv[k] = *(const float4*)(z + (size_t)tok[k] * Zd + 4 * c);
#pragma unroll
        for (int r = 0; r < Rr; ++r) {
            const float4 w = A1[r * (Zd / 4) + c];
#pragma unroll
            for (int k = 0; k < TW; ++k)
                p[k][r] = fmaf(zv[k].x, w.x, fmaf(zv[k].y, w.y,
                          fmaf(zv[k].z, w.z, fmaf(zv[k].w, w.w, p[k][r]))));
        }
    }
    float t1[TW][Rr];
#pragma unroll
    for (int k = 0; k < TW; ++k)
#pragma unroll
        for (int r = 0; r < Rr; ++r) t1[k][r] = wave_allreduce(p[k][r]);

    // ---------- Phase 2: 8 chunks, 3-deep counted-vmcnt pipeline ----------
    float q[TW][Rr];
#pragma unroll
    for (int k = 0; k < TW; ++k)
#pragma unroll
        for (int r = 0; r < Rr; ++r) q[k][r] = 0.f;

#pragma unroll
    for (int kc = 0; kc < NCHUNK; ++kc) {
        // Outstanding newer than own stage(kc): next stage pair [2] + hv [2].
        WAITVM(4);
        SYNC();        // all waves' stage(kc) landed; rotated buf reads done

        if (kc + 2 < NCHUNK) {      // stage chunk kc+2 into buf (kc+2)%3
            const int nb = (kc + 2) % 3;
            const int hb = (kc + 2) * HC;
            stage16(b1e + (size_t)hb * Rr * 4 + swz(t * 16),
                    pool + kSB[nb] + wave * 1024);
            stage16(a2e + wave * Hd + hb + lane * 4,
                    pool + kSB[nb] + 8192 + wave * 1024);
        } else {
            // kc=6: b2 segs 0,1 -> bytes [0,16K) (buf2's slots, freed)
            // kc=7: b2 segs 2,3 -> bytes [16K,32K) (buf0's slots, freed)
            const int sbase = (kc - 6) * 2;
            stage16(b2e + (size_t)sbase * 8192 + swz(t * 16),
                    pool + sbase * 8192 + wave * 1024);
            stage16(b2e + (size_t)(sbase + 1) * 8192 + swz(t * 16),
                    pool + (sbase + 1) * 8192 + wave * 1024);
        }
        if (kc + 1 < NCHUNK) {      // hv register-prefetch for next chunk
            const int cc = (kc + 1) * 64 + lane;
#pragma unroll
            for (int k = 0; k < TW; ++k)
                hv[(kc + 1) & 1][k] =
                    *(const float4*)(h_pre + (size_t)tok[k] * Hd + 4 * cc);
        }

        const int cb = kSB[kc % 3];
        float sv[TW][4];
#pragma unroll
        for (int j = 0; j < 4; ++j) {
            const int o0 = lane * 128 + j * 32;     // row (4*lane+j) of chunk
            const float4 w0 = *(const float4*)(pool + cb + swz(o0));
            const float4 w1 = *(const float4*)(pool + cb + swz(o0 + 16));
#pragma unroll
            for (int k = 0; k < TW; ++k) {
                const float x = (&hv[kc & 1][k].x)[j] + dot8(t1[k], w0, w1) * kScale;
                sv[k][j] = silu(x);
            }
        }
#pragma unroll
        for (int r = 0; r < Rr; ++r) {
            const float4 aw = *(const float4*)(pool + cb + 8192 + r * 1024 + lane * 16);
#pragma unroll
            for (int k = 0; k < TW; ++k)
                q[k][r] = fmaf(sv[k][0], aw.x, fmaf(sv[k][1], aw.y,
                          fmaf(sv[k][2], aw.z, fmaf(sv[k][3], aw.w, q[k][r]))));
        }
    }

    float t2[TW][Rr];
#pragma unroll
    for (int k = 0; k < TW; ++k)
#pragma unroll
        for (int r = 0; r < Rr; ++r) t2[k][r] = wave_allreduce(q[k][r]) * kScale;

    WAITVM(0);     // all b2 segments landed
    SYNC();        // ... for every wave

    // ---------- Phase 3: out = out_pre + t2·b2[e,d,:]  (b2 flat in pool) ----
#pragma unroll
    for (int i = 0; i < Zd / 4 / 64; ++i) {         // 4 iters
        const int c = lane + i * 64;
        float4 ov[TW];
#pragma unroll
        for (int k = 0; k < TW; ++k)
            ov[k] = *(const float4*)(out_pre + (size_t)tok[k] * Zd + 4 * c);
        float4 res[TW];
#pragma unroll
        for (int j = 0; j < 4; ++j) {
            const int o0 = c * 128 + j * 32;        // row (4c+j), 32 B each
            const float4 w0 = *(const float4*)(pool + swz(o0));
            const float4 w1 = *(const float4*)(pool + swz(o0 + 16));
#pragma unroll
            for (int k = 0; k < TW; ++k)
                (&res[k].x)[j] = (&ov[k].x)[j] + dot8(t2[k], w0, w1);
        }
#pragma unroll
        for (int k = 0; k < TW; ++k)
            if (val[k]) *(float4*)(out + (size_t)tok[k] * Zd + 4 * c) = res[k];
    }
}

extern "C" void kernel_launch(void* const* d_in, const int* in_sizes, int n_in,
                              void* d_out, int out_size, void* d_ws, size_t ws_size,
                              hipStream_t stream) {
    const float* z       = (const float*)d_in[0];
    const int*   a_idx   = (const int*)d_in[1];
    const float* h_pre   = (const float*)d_in[2];
    const float* out_pre = (const float*)d_in[3];
    const float* a1      = (const float*)d_in[4];
    const float* b1      = (const float*)d_in[5];
    const float* a2      = (const float*)d_in[6];
    const float* b2      = (const float*)d_in[7];
    float* out = (float*)d_out;

    const int N = in_sizes[1];  // a_idx count

    bucket_kernel<<<1, 1024, 0, stream>>>(a_idx, N, (int*)d_ws);

    int nwg = N / TB + Wn;              // 576 blocks (incl. per-expert tails)
    nwg = (nwg + 7) & ~7;               // multiple of 8 for XCD swizzle
    lora_main<<<nwg, NT, 0, stream>>>(z, h_pre, out_pre, a1, b1, a2, b2, out,
                                      (const int*)d_ws, N);
}